// Round 6
// baseline (1319.585 us; speedup 1.0000x reference)
//
#include <hip/hip_runtime.h>
#include <math.h>

#define TT 12
#define NN 20000
#define EE 320000

__device__ __forceinline__ float wsum64(float v) {
#pragma unroll
    for (int o = 32; o >= 1; o >>= 1) v += __shfl_xor(v, o);
    return v;
}

__device__ __forceinline__ float wsum16(float v) {
#pragma unroll
    for (int o = 8; o >= 1; o >>= 1) v += __shfl_xor(v, o);
    return v;
}

// broadcast lane l's value to all lanes via SGPR (VALU pipe, no LDS)
__device__ __forceinline__ float rdlane(float v, int l) {
    return __int_as_float(__builtin_amdgcn_readlane(__float_as_int(v), l));
}

// ---------------- transformer algebra precompute ----------------
// PC layout (floats): Vo0..3 @0..255, C0 @256..319,
// alpha @320..323, beta @324..327, gamma @328..331, delta @332..335,
// P[8][256] @384..2431
// P rows: r=0: Wpi*g1 (coeff sv*iv), r=1..4: Vo0..3*g1 (coeff cv0..3*iv),
//         r=5: C0*g1 (coeff iv), r=6: g1 (coeff -m*iv), r=7: be1@W1+b1 (coeff 1)
__global__ void k_precomp(const float* __restrict__ Wpi, const float* __restrict__ bpi,
                          const float* __restrict__ Wq, const float* __restrict__ bq,
                          const float* __restrict__ Wk, const float* __restrict__ bk,
                          const float* __restrict__ Wv, const float* __restrict__ bv,
                          const float* __restrict__ Wo, const float* __restrict__ bo,
                          const float* __restrict__ g1, const float* __restrict__ be1,
                          const float* __restrict__ W1, const float* __restrict__ b1,
                          float* __restrict__ PC) {
    __shared__ float sWq[64], sWk[64], sWv[64], sBq[64], sBk[64], sBv[64];
    const int tid = threadIdx.x;
    if (tid < 64) {
        int d = tid;
        float wq = 0, wk = 0, wv = 0, vbq = 0, vbk = 0, vbv = 0;
        for (int e = 0; e < 64; ++e) {
            float wp = Wpi[e], bp = bpi[e];
            wq = fmaf(wp, Wq[e * 64 + d], wq);
            wk = fmaf(wp, Wk[e * 64 + d], wk);
            wv = fmaf(wp, Wv[e * 64 + d], wv);
            vbq = fmaf(bp, Wq[e * 64 + d], vbq);
            vbk = fmaf(bp, Wk[e * 64 + d], vbk);
            vbv = fmaf(bp, Wv[e * 64 + d], vbv);
        }
        sWq[d] = wq; sWk[d] = wk; sWv[d] = wv;
        sBq[d] = vbq + bq[d]; sBk[d] = vbk + bk[d]; sBv[d] = vbv + bv[d];
    }
    __syncthreads();
    if (tid < 16) {
        int h = tid >> 2, which = tid & 3;
        float s = 0;
        for (int j = 0; j < 16; ++j) {
            int e = h * 16 + j;
            float a = (which < 2) ? sWq[e] : sBq[e];
            float b = (which & 1) ? sBk[e] : sWk[e];
            s = fmaf(a, b, s);
        }
        PC[320 + which * 4 + h] = s;
    }
    {   // Vo_h[d]
        int h = tid >> 6, d = tid & 63;
        float s = 0;
        for (int j = 0; j < 16; ++j) {
            int e = h * 16 + j;
            s = fmaf(sWv[e], Wo[e * 64 + d], s);
        }
        PC[h * 64 + d] = s;
    }
    if (tid < 64) {
        int d = tid;
        float s = 0;
        for (int e = 0; e < 64; ++e) s = fmaf(sBv[e], Wo[e * 64 + d], s);
        PC[256 + d] = s + bo[d] + bpi[d];   // C0 = bpi + (bv_eff@Wo + bo)
    }
    __syncthreads();
    {
        int k = tid;
        for (int r = 0; r < 8; ++r) {
            float s = (r == 7) ? b1[k] : 0.0f;
            for (int d = 0; d < 64; ++d) {
                float b;
                if (r == 0) b = Wpi[d] * g1[d];
                else if (r < 5) b = PC[(r - 1) * 64 + d] * g1[d];
                else if (r == 5) b = PC[256 + d] * g1[d];
                else if (r == 6) b = g1[d];
                else b = be1[d];
                s = fmaf(b, W1[d * 256 + k], s);
            }
            PC[384 + r * 256 + k] = s;
        }
    }
}

// ---------------- CSR build ----------------
__global__ void k_zero_offs(int* __restrict__ offs) {
    int i = blockIdx.x * 256 + threadIdx.x;
    if (i < NN + 1) offs[i] = 0;
}
__global__ void k_count(const int* __restrict__ dst, int* __restrict__ offs) {
    int e = blockIdx.x * 256 + threadIdx.x;
    if (e < EE) atomicAdd(&offs[dst[e] + 1], 1);
}
__global__ void k_scan(int* __restrict__ offs, int* __restrict__ cur) {
    __shared__ int buf[1024];
    __shared__ int carry;
    int tid = threadIdx.x;
    if (tid == 0) carry = 0;
    __syncthreads();
    const int total = NN + 1;
    for (int base = 0; base < total; base += 1024) {
        int idx = base + tid;
        int v = (idx < total) ? offs[idx] : 0;
        buf[tid] = v;
        __syncthreads();
        for (int o = 1; o < 1024; o <<= 1) {
            int t = (tid >= o) ? buf[tid - o] : 0;
            __syncthreads();
            buf[tid] += t;
            __syncthreads();
        }
        int incl = buf[tid] + carry;
        if (idx < total) offs[idx] = incl;
        __syncthreads();
        if (tid == 1023) carry += buf[1023];
        __syncthreads();
    }
    for (int i = tid; i < NN; i += 1024) cur[i] = offs[i];
}
__global__ void k_fill(const int* __restrict__ src, const int* __restrict__ dst,
                       const float* __restrict__ w, int* __restrict__ cur,
                       int2* __restrict__ ep) {
    int e = blockIdx.x * 256 + threadIdx.x;
    if (e < EE) {
        int dn = dst[e];
        int slot = atomicAdd(&cur[dn], 1);
        ep[slot] = make_int2(src[e], __float_as_int(w[e]));
    }
}

// ---------------- fused per-node transformer (rank-collapsed, chunked W2, no spill) --------
// grid 5000 x 256; wave = node; lane = feature d.  XS node-major [n][12].
__global__ void __launch_bounds__(256)
k_transformer(const float* __restrict__ x_seq,
              const float* __restrict__ Wpi,
              const float* __restrict__ g1, const float* __restrict__ be1,
              const float* __restrict__ b2,
              const float* __restrict__ g2, const float* __restrict__ be2,
              const float* __restrict__ W2,
              const float* __restrict__ PC,
              const float* __restrict__ Wpo, const float* __restrict__ bpo,
              float* __restrict__ XS) {
    __shared__ __align__(16) float sCV[4][TT][4];
    __shared__ __align__(16) float sRelu[4][TT][64];
    __shared__ __align__(16) float sX1[4][TT][64];
    __shared__ float sIvsv[4][TT];
    __shared__ float sMiv[4][TT];
    const int wid = threadIdx.x >> 6;
    const int d = threadIdx.x & 63;
    const int n = blockIdx.x * 4 + wid;

    // input scalars (broadcast loads)
    float sv[TT];
#pragma unroll
    for (int t = 0; t < TT; ++t) sv[t] = x_seq[t * NN + n];

    // attention: lane = (head hh, query qi); scores from scalar algebra
    {
        const int hh = d >> 4;
        const int qi = d & 15;
        const float alpha = PC[320 + hh], beta = PC[324 + hh];
        const float gamma = PC[328 + hh], delta = PC[332 + hh];
        if (qi < TT) {
            float si = sv[qi];
            float a1 = 0.25f * fmaf(si, alpha, gamma);
            float a0 = 0.25f * fmaf(si, beta, delta);
            float sc[TT];
            float mx = -1e30f;
#pragma unroll
            for (int j = 0; j < TT; ++j) {
                sc[j] = fmaf(sv[j], a1, a0);
                mx = fmaxf(mx, sc[j]);
            }
            float ssum = 0.f;
#pragma unroll
            for (int j = 0; j < TT; ++j) { sc[j] = __expf(sc[j] - mx); ssum += sc[j]; }
            float inv = 1.0f / ssum;
            float cv = 0.f;
#pragma unroll
            for (int j = 0; j < TT; ++j) cv = fmaf(sc[j] * inv, sv[j], cv);
            sCV[wid][qi][hh] = cv;
        }
    }
    __syncthreads();

    // y = s*u + sum_h cv_h*Vo_h + C0 ; LN1. Keep only ivv in regs; x1 -> LDS.
    float ivv[TT];
    const float inv64 = 1.0f / 64.0f;
    {
        const float u = Wpi[d];
        const float g1d = g1[d], be1d = be1[d];
        const float vo0 = PC[d], vo1 = PC[64 + d], vo2 = PC[128 + d], vo3 = PC[192 + d];
        const float c0 = PC[256 + d];
#pragma unroll
        for (int t = 0; t < TT; ++t) {
            float4 cv4 = *(const float4*)(&sCV[wid][t][0]);
            float y = fmaf(sv[t], u, c0);
            y = fmaf(cv4.x, vo0, y); y = fmaf(cv4.y, vo1, y);
            y = fmaf(cv4.z, vo2, y); y = fmaf(cv4.w, vo3, y);
            float s1 = wsum64(y);
            float s2 = wsum64(y * y);
            float m = s1 * inv64;
            float var = s2 * inv64 - m * m;
            float iv = rsqrtf(var + 1e-5f);
            ivv[t] = iv;
            sX1[wid][t][d] = (y - m) * iv * g1d + be1d;
            if (d == 0) {
                sIvsv[wid][t] = sv[t] * iv;   // sv uniform across lanes
                sMiv[wid][t] = -m * iv;
            }
        }
    }
    // wave-private LDS, no barrier needed

    // FFN: per 64-col chunk kk: rank-8 relu chunk -> LDS -> coalesced-W2 accumulate
    float y2[TT];
    {
        float b2d = b2[d];
#pragma unroll
        for (int t = 0; t < TT; ++t) y2[t] = b2d;
    }
#pragma unroll
    for (int kk = 0; kk < 4; ++kk) {
        const float* P = PC + 384 + kk * 64 + d;
        float P0 = P[0], P1 = P[256], P2 = P[512], P3 = P[768];
        float P4 = P[1024], P5 = P[1280], P6 = P[1536], P7 = P[1792];
#pragma unroll
        for (int t = 0; t < TT; ++t) {
            float4 cv4 = *(const float4*)(&sCV[wid][t][0]);
            float iv = ivv[t];
            float hp = P7;
            hp = fmaf(sIvsv[wid][t], P0, hp);
            hp = fmaf(cv4.x * iv, P1, hp);
            hp = fmaf(cv4.y * iv, P2, hp);
            hp = fmaf(cv4.z * iv, P3, hp);
            hp = fmaf(cv4.w * iv, P4, hp);   // cv3*iv <-> Vo3 row
            hp = fmaf(iv, P5, hp);           // iv     <-> C0 row
            hp = fmaf(sMiv[wid][t], P6, hp);
            sRelu[wid][t][d] = fmaxf(hp, 0.0f);
        }
        // wave-private LDS: no barrier needed
#pragma unroll 4
        for (int kg = 0; kg < 64; kg += 4) {
            const float* wb = W2 + (kk * 64 + kg) * 64 + d;
            float w0 = wb[0], w1 = wb[64], w2 = wb[128], w3 = wb[192];
#pragma unroll
            for (int t = 0; t < TT; ++t) {
                float4 rv = *(const float4*)(&sRelu[wid][t][kg]);
                y2[t] = fmaf(rv.x, w0, fmaf(rv.y, w1, fmaf(rv.z, w2, fmaf(rv.w, w3, y2[t]))));
            }
        }
    }

    // LN2 + output head
    {
        float g2d = g2[d], be2d = be2[d], wpod = Wpo[d];
        float bpo0 = bpo[0];
#pragma unroll
        for (int t = 0; t < TT; ++t) {
            float y = sX1[wid][t][d] + y2[t];
            float s1 = wsum64(y);
            float s2 = wsum64(y * y);
            float m = s1 * inv64;
            float var = s2 * inv64 - m * m;
            float iv = rsqrtf(var + 1e-5f);
            float x2 = (y - m) * iv * g2d + be2d;
            float p = wsum64(x2 * wpod);
            if (d == 0) XS[n * TT + t] = p + bpo0;
        }
    }
}

// ---------------- precompute msg_x for ALL timesteps ----------------
__global__ void k_gather_x(const float* __restrict__ XS,
                           const int* __restrict__ offs, const int2* __restrict__ ep,
                           float* __restrict__ MX) {
    const int wid = threadIdx.x >> 6;
    const int lane = threadIdx.x & 63;
    const int lg = lane >> 4;
    const int el = lane & 15;
    const int n = (blockIdx.x * 4 + wid) * 4 + lg;
    int beg = offs[n], end = offs[n + 1];
    float4 a0 = {0,0,0,0}, a1 = {0,0,0,0}, a2 = {0,0,0,0};
    for (int i = beg + el; i < end; i += 16) {
        int2 e = ep[i];
        float w = __int_as_float(e.y);
        const float4* xr = (const float4*)(XS + (size_t)e.x * TT);
        float4 v0 = xr[0], v1 = xr[1], v2 = xr[2];
        a0.x = fmaf(w, v0.x, a0.x); a0.y = fmaf(w, v0.y, a0.y);
        a0.z = fmaf(w, v0.z, a0.z); a0.w = fmaf(w, v0.w, a0.w);
        a1.x = fmaf(w, v1.x, a1.x); a1.y = fmaf(w, v1.y, a1.y);
        a1.z = fmaf(w, v1.z, a1.z); a1.w = fmaf(w, v1.w, a1.w);
        a2.x = fmaf(w, v2.x, a2.x); a2.y = fmaf(w, v2.y, a2.y);
        a2.z = fmaf(w, v2.z, a2.z); a2.w = fmaf(w, v2.w, a2.w);
    }
    float acc[TT] = { a0.x, a0.y, a0.z, a0.w, a1.x, a1.y, a1.z, a1.w,
                      a2.x, a2.y, a2.z, a2.w };
#pragma unroll
    for (int t = 0; t < TT; ++t) acc[t] = wsum16(acc[t]);
    if (el == 0) {
#pragma unroll
        for (int t = 0; t < TT; ++t) MX[n * TT + t] = acc[t];
    }
}

// ============ fused GRU phase kernels: block = 16 nodes ============
// Phase 1 (gather): block edge range is contiguous [offs[nb], offs[nb+16]).
// Each wave takes a contiguous quarter; edge cursor i is WAVE-UNIFORM so all
// 64 lanes issue one coalesced 256B row load per edge (independent stream ->
// deep ILP). Partials go to per-wave LDS banks; monotonic node-cursor flush.
// Phase 2 (gates): 4 nodes/wave readlane GEMV (identical math to r4/r5).

__device__ __forceinline__ void gather16(const float* __restrict__ V,
                                         const int2* __restrict__ ep,
                                         const int* __restrict__ soffs,
                                         float (*part)[16][64],
                                         int wid, int d) {
    // zero own bank
#pragma unroll
    for (int g = 0; g < 16; ++g) part[wid][g][d] = 0.f;

    int e0i = soffs[0], e16 = soffs[16];
    int E = e16 - e0i;
    int chunk = (E + 3) >> 2;
    int ib = e0i + wid * chunk;
    int ie = min(ib + chunk, e16);

    float acc = 0.f;
    int g = 0;
    int i = ib;
    for (; i + 2 <= ie; i += 2) {
        int2 ea = ep[i], eb = ep[i + 1];
        float ra = V[(size_t)ea.x * 64 + d];
        float rb = V[(size_t)eb.x * 64 + d];
        while (i >= soffs[g + 1]) { part[wid][g][d] = acc; acc = 0.f; ++g; }
        acc = fmaf(__int_as_float(ea.y), ra, acc);
        while (i + 1 >= soffs[g + 1]) { part[wid][g][d] = acc; acc = 0.f; ++g; }
        acc = fmaf(__int_as_float(eb.y), rb, acc);
    }
    for (; i < ie; ++i) {
        int2 e = ep[i];
        float r = V[(size_t)e.x * 64 + d];
        while (i >= soffs[g + 1]) { part[wid][g][d] = acc; acc = 0.f; ++g; }
        acc = fmaf(__int_as_float(e.y), r, acc);
    }
    if (ib < ie) part[wid][g][d] = acc;
}

__global__ void __launch_bounds__(256)
k_gru_a(const float* __restrict__ XS, const float* __restrict__ MX, int tstep,
        const float* __restrict__ h,
        const int* __restrict__ offs, const int2* __restrict__ ep,
        const float* __restrict__ Az, const float* __restrict__ Bz,
        const float* __restrict__ bz,
        const float* __restrict__ Cz, const float* __restrict__ Dz,
        const float* __restrict__ cz,
        const float* __restrict__ Ar, const float* __restrict__ Br,
        const float* __restrict__ br,
        const float* __restrict__ Cr, const float* __restrict__ Dr,
        const float* __restrict__ cr,
        float* __restrict__ zb, float* __restrict__ rh) {
    __shared__ __align__(16) float part[4][16][64];
    __shared__ int soffs[17];
    const int wid = threadIdx.x >> 6;
    const int d = threadIdx.x & 63;
    const int nb = blockIdx.x * 16;
    if (threadIdx.x < 17) soffs[threadIdx.x] = offs[nb + threadIdx.x];
    __syncthreads();

    gather16(h, ep, soffs, part, wid, d);
    __syncthreads();

    float hreg[4], mreg[4], zacc[4], racc[4];
    {
        float azd = Az[d], bzd = Bz[d], cz0 = bz[d] + cz[d];
        float ard = Ar[d], brd = Br[d], cr0 = br[d] + cr[d];
#pragma unroll
        for (int g = 0; g < 4; ++g) {
            int gl = wid * 4 + g;
            int n = nb + gl;
            hreg[g] = h[(size_t)n * 64 + d];
            mreg[g] = part[0][gl][d] + part[1][gl][d] + part[2][gl][d] + part[3][gl][d];
            float xt = XS[n * TT + tstep];
            float mx = MX[n * TT + tstep];
            zacc[g] = fmaf(xt, azd, fmaf(mx, bzd, cz0));
            racc[g] = fmaf(xt, ard, fmaf(mx, brd, cr0));
        }
    }
#pragma unroll 4
    for (int k = 0; k < 64; ++k) {
        float wcz = Cz[k * 64 + d], wdz = Dz[k * 64 + d];
        float wcr = Cr[k * 64 + d], wdr = Dr[k * 64 + d];
#pragma unroll
        for (int g = 0; g < 4; ++g) {
            float hk = rdlane(hreg[g], k);
            float mk = rdlane(mreg[g], k);
            zacc[g] = fmaf(hk, wcz, fmaf(mk, wdz, zacc[g]));
            racc[g] = fmaf(hk, wcr, fmaf(mk, wdr, racc[g]));
        }
    }
#pragma unroll
    for (int g = 0; g < 4; ++g) {
        int n = nb + wid * 4 + g;
        float z = 1.0f / (1.0f + __expf(-zacc[g]));
        float r = 1.0f / (1.0f + __expf(-racc[g]));
        zb[(size_t)n * 64 + d] = z;
        rh[(size_t)n * 64 + d] = r * hreg[g];
    }
}

__global__ void __launch_bounds__(256)
k_gru_b(const float* __restrict__ XS, const float* __restrict__ MX, int tstep,
        float* __restrict__ h,
        const float* __restrict__ zb, const float* __restrict__ rh,
        const int* __restrict__ offs, const int2* __restrict__ ep,
        const float* __restrict__ Ah, const float* __restrict__ Bh,
        const float* __restrict__ bg,
        const float* __restrict__ Ch, const float* __restrict__ Dh,
        const float* __restrict__ cg,
        const float* __restrict__ Whd, const float* __restrict__ bhd,
        float* __restrict__ out, int last) {
    __shared__ __align__(16) float part[4][16][64];
    __shared__ int soffs[17];
    const int wid = threadIdx.x >> 6;
    const int d = threadIdx.x & 63;
    const int nb = blockIdx.x * 16;
    if (threadIdx.x < 17) soffs[threadIdx.x] = offs[nb + threadIdx.x];
    __syncthreads();

    gather16(rh, ep, soffs, part, wid, d);
    __syncthreads();

    float rreg[4], mreg[4], gacc[4];
    {
        float ahd = Ah[d], bhd_ = Bh[d], cg0 = bg[d] + cg[d];
#pragma unroll
        for (int g = 0; g < 4; ++g) {
            int gl = wid * 4 + g;
            int n = nb + gl;
            rreg[g] = rh[(size_t)n * 64 + d];
            mreg[g] = part[0][gl][d] + part[1][gl][d] + part[2][gl][d] + part[3][gl][d];
            float xt = XS[n * TT + tstep];
            float mx = MX[n * TT + tstep];
            gacc[g] = fmaf(xt, ahd, fmaf(mx, bhd_, cg0));
        }
    }
#pragma unroll 4
    for (int k = 0; k < 64; ++k) {
        float wch = Ch[k * 64 + d], wdh = Dh[k * 64 + d];
#pragma unroll
        for (int g = 0; g < 4; ++g) {
            float rk = rdlane(rreg[g], k);
            float mk = rdlane(mreg[g], k);
            gacc[g] = fmaf(rk, wch, fmaf(mk, wdh, gacc[g]));
        }
    }
#pragma unroll
    for (int g = 0; g < 4; ++g) {
        int n = nb + wid * 4 + g;
        float gg = tanhf(gacc[g]);
        float z = zb[(size_t)n * 64 + d];
        float hold = h[(size_t)n * 64 + d];
        float hnew = z * hold + (1.0f - z) * gg;
        h[(size_t)n * 64 + d] = hnew;
        if (last) {
            float p = fmaxf(hnew, 0.0f) * Whd[d];
            float s = wsum64(p);
            if (d == 0) out[n] = s + bhd[0];
        }
    }
}

extern "C" void kernel_launch(void* const* d_in, const int* in_sizes, int n_in,
                              void* d_out, int out_size, void* d_ws, size_t ws_size,
                              hipStream_t stream) {
    const float* x_seq = (const float*)d_in[0];
    const int* eidx = (const int*)d_in[1];
    const float* ew = (const float*)d_in[2];
    const float* Wpi = (const float*)d_in[3];
    const float* bpi = (const float*)d_in[4];
    const float* Wq = (const float*)d_in[5];
    const float* Wk = (const float*)d_in[6];
    const float* Wv = (const float*)d_in[7];
    const float* Wo = (const float*)d_in[8];
    const float* W1 = (const float*)d_in[9];
    const float* W2 = (const float*)d_in[10];
    const float* Wpo = (const float*)d_in[11];
    const float* bq = (const float*)d_in[12];
    const float* bk = (const float*)d_in[13];
    const float* bv = (const float*)d_in[14];
    const float* bo = (const float*)d_in[15];
    const float* b1 = (const float*)d_in[16];
    const float* b2 = (const float*)d_in[17];
    const float* bpo = (const float*)d_in[18];
    const float* g1 = (const float*)d_in[19];
    const float* be1 = (const float*)d_in[20];
    const float* g2 = (const float*)d_in[21];
    const float* be2 = (const float*)d_in[22];
    const float* Az = (const float*)d_in[23];
    const float* Bz = (const float*)d_in[24];
    const float* bz = (const float*)d_in[25];
    const float* Cz = (const float*)d_in[26];
    const float* Dz = (const float*)d_in[27];
    const float* cz = (const float*)d_in[28];
    const float* Ar = (const float*)d_in[29];
    const float* Br = (const float*)d_in[30];
    const float* br_ = (const float*)d_in[31];
    const float* Cr = (const float*)d_in[32];
    const float* Dr = (const float*)d_in[33];
    const float* cr_ = (const float*)d_in[34];
    const float* Ah = (const float*)d_in[35];
    const float* Bh = (const float*)d_in[36];
    const float* bg = (const float*)d_in[37];
    const float* Ch = (const float*)d_in[38];
    const float* Dh = (const float*)d_in[39];
    const float* cg = (const float*)d_in[40];
    const float* Whd = (const float*)d_in[41];
    const float* bhd = (const float*)d_in[42];

    float* ws = (float*)d_ws;
    float* XS = ws;                         // 240000 (node-major [n][12])
    float* hbuf = XS + 240000;              // 1280000
    float* rhbuf = hbuf + 1280000;          // 1280000
    float* zbuf = rhbuf + 1280000;          // 1280000
    float* PC = zbuf + 1280000;             // 2560
    int* ioffs = (int*)(PC + 2560);         // NN+1
    int* cur = ioffs + (NN + 1);            // NN (+1 pad)
    int2* ep = (int2*)(cur + NN + 1);       // EE int2
    float* MX = (float*)(ep + EE);          // 240000 (node-major)

    const int* e_src = eidx;
    const int* e_dst = eidx + EE;

    hipMemsetAsync(hbuf, 0, (size_t)NN * 64 * sizeof(float), stream);
    k_precomp<<<1, 256, 0, stream>>>(Wpi, bpi, Wq, bq, Wk, bk, Wv, bv, Wo, bo,
                                     g1, be1, W1, b1, PC);
    k_zero_offs<<<(NN + 1 + 255) / 256, 256, 0, stream>>>(ioffs);
    k_count<<<(EE + 255) / 256, 256, 0, stream>>>(e_dst, ioffs);
    k_scan<<<1, 1024, 0, stream>>>(ioffs, cur);
    k_fill<<<(EE + 255) / 256, 256, 0, stream>>>(e_src, e_dst, ew, cur, ep);

    k_transformer<<<5000, 256, 0, stream>>>(x_seq, Wpi, g1, be1, b2, g2, be2,
                                            W2, PC, Wpo, bpo, XS);

    k_gather_x<<<1250, 256, 0, stream>>>(XS, ioffs, ep, MX);

    for (int t = 0; t < TT; ++t) {
        k_gru_a<<<1250, 256, 0, stream>>>(XS, MX, t, hbuf, ioffs, ep,
                                          Az, Bz, bz, Cz, Dz, cz,
                                          Ar, Br, br_, Cr, Dr, cr_,
                                          zbuf, rhbuf);
        k_gru_b<<<1250, 256, 0, stream>>>(XS, MX, t, hbuf, zbuf, rhbuf, ioffs, ep,
                                          Ah, Bh, bg, Ch, Dh, cg,
                                          Whd, bhd, (float*)d_out, (t == TT - 1) ? 1 : 0);
    }
}